// Round 9
// baseline (897.625 us; speedup 1.0000x reference)
//
#include <hip/hip_runtime.h>
#include <hip/hip_bf16.h>

// Problem constants (GraphGRUCell_62019327754706)
// DTYPES (settled r4/r5): all float tensors FP32 in and out. int32 edges.
// r6: never clamp launch_bounds waves -> spills. r7: weight re-streaming is
// the dense-side cost. r8: bf16 k/v + node-batching works (absmax 0.016).
// r9: 8 nodes/wave, block=64 (wave-private LDS, cheap barriers), float4 LDS
// reads, (p,voff)-pair phase B, register-chunked parallel scan.
#define BB 4
#define NN 20000
#define UU 64
#define EE 640000
#define FF 65              // U + D
#define SCALE_F 0.125f     // 1/sqrt(64)
#define NEG_F  -1e30f

typedef unsigned short u16;

static inline size_t align_up(size_t x) { return (x + 255) & ~(size_t)255; }

__device__ __forceinline__ float u2f(unsigned int u) { return __uint_as_float(u); }
__device__ __forceinline__ u16 f2bf(float f) {
    __hip_bfloat16 h = __float2bfloat16(f);
    return *reinterpret_cast<u16*>(&h);
}

// ---------------------------------------------------------------- CSR build
__global__ __launch_bounds__(256) void hist_kernel(const int* __restrict__ edst,
                                                   int* __restrict__ counts) {
    int e = blockIdx.x * 256 + threadIdx.x;
    if (e < EE) {
        int d = edst[e];
        if ((unsigned)d < (unsigned)NN) atomicAdd(&counts[d], 1);
    }
}

// One block, 20 elements/thread in registers -> single 1024-wide scan.
__global__ __launch_bounds__(1024) void scan_kernel(const int* __restrict__ counts,
                                                    int* __restrict__ off,
                                                    int* __restrict__ cursor) {
    __shared__ int sd[1024];
    int tid = threadIdx.x;
    int base = tid * 20;
    int loc[20];
    int s = 0;
#pragma unroll
    for (int k = 0; k < 20; ++k) {
        int i = base + k;
        int v = (i < NN) ? counts[i] : 0;
        loc[k] = s;                       // exclusive within thread
        s += v;
    }
    sd[tid] = s;
    __syncthreads();
    for (int d = 1; d < 1024; d <<= 1) {  // Hillis-Steele inclusive
        int t = (tid >= d) ? sd[tid - d] : 0;
        __syncthreads();
        sd[tid] += t;
        __syncthreads();
    }
    int excl = sd[tid] - s;
#pragma unroll
    for (int k = 0; k < 20; ++k) {
        int i = base + k;
        if (i < NN) { int o = excl + loc[k]; off[i] = o; cursor[i] = o; }
    }
    if (tid == 1023) off[NN] = sd[1023];  // == EE
}

__global__ __launch_bounds__(256) void scatter_kernel(const int* __restrict__ edst,
                                                      const int* __restrict__ esrc,
                                                      int* __restrict__ cursor,
                                                      int* __restrict__ psrc) {
    int e = blockIdx.x * 256 + threadIdx.x;
    if (e < EE) {
        int d = edst[e];
        if ((unsigned)d < (unsigned)NN) {
            int p = atomicAdd(&cursor[d], 1);
            if ((unsigned)p < (unsigned)EE) psrc[p] = esrc[e];
        }
    }
}

// ----------------------------- prep: k,v (bf16) + mask, 8 nodes per wave
__global__ __launch_bounds__(64) void prep_kernel(
    const float* __restrict__ state, const float* __restrict__ inputs,
    const float* __restrict__ Wk, const float* __restrict__ bk,
    const float* __restrict__ Wv, const float* __restrict__ bv,
    u16* __restrict__ kbuf, u16* __restrict__ vbuf,
    unsigned char* __restrict__ maskb) {
    int lane = threadIdx.x;
    int gb = blockIdx.x * 8;
    __shared__ __align__(16) float xs[8][68];
    float hv8[8], xin8[8];
#pragma unroll
    for (int j = 0; j < 8; ++j) {
        hv8[j] = state[(size_t)(gb + j) * UU + lane];
        xs[j][lane] = hv8[j];
    }
#pragma unroll
    for (int j = 0; j < 8; ++j) xin8[j] = inputs[gb + j];
    __syncthreads();

    float ak[8], av[8];
#pragma unroll
    for (int j = 0; j < 8; ++j) { ak[j] = 0.f; av[j] = 0.f; }
    for (int f4 = 0; f4 < 16; ++f4) {
        float4 xv[8];
#pragma unroll
        for (int j = 0; j < 8; ++j) xv[j] = *(const float4*)&xs[j][f4 * 4];
#pragma unroll
        for (int ff = 0; ff < 4; ++ff) {
            int f = f4 * 4 + ff;
            float wk = Wk[f * UU + lane], wv = Wv[f * UU + lane];
#pragma unroll
            for (int j = 0; j < 8; ++j) {
                float xf = ff == 0 ? xv[j].x : ff == 1 ? xv[j].y
                         : ff == 2 ? xv[j].z : xv[j].w;
                ak[j] += xf * wk; av[j] += xf * wv;
            }
        }
    }
    float wk64 = Wk[UU * UU + lane], wv64 = Wv[UU * UU + lane];
    float bkl = bk[lane], bvl = bv[lane];
#pragma unroll
    for (int j = 0; j < 8; ++j) {
        int g = gb + j;
        kbuf[(size_t)g * UU + lane] = f2bf(ak[j] + xin8[j] * wk64 + bkl);
        vbuf[(size_t)g * UU + lane] = f2bf(av[j] + xin8[j] * wv64 + bvl);
        float mk = __shfl(hv8[j], 58, 64);
        if (lane == 0) maskb[g] = (mk != 0.0f) ? 1 : 0;
    }
}

// -------------------- fused: 8 nodes/wave, block=64, bf16 k/v, GRU
__global__ __launch_bounds__(64) void fused_fast(
    const float* __restrict__ state, const float* __restrict__ inputs,
    const float* __restrict__ Wq, const float* __restrict__ bq,
    const float* __restrict__ Ws, const float* __restrict__ bs,
    const float* __restrict__ W1, const float* __restrict__ b1,
    const float* __restrict__ W2, const float* __restrict__ b2,
    const u16* __restrict__ kbuf, const u16* __restrict__ vbuf,
    const unsigned char* __restrict__ maskb,
    const int* __restrict__ off, const int* __restrict__ psrc,
    float* __restrict__ out) {
    int lane = threadIdx.x;
    int gb = blockIdx.x * 8;                  // 8 nodes, same batch (NN%8==0)
    int b = gb / NN;
    __shared__ __align__(16) float buf[8][68];  // x -> q -> h2 -> r*h2 rows
    __shared__ __align__(16) float pv[128];     // 64 (p, voff) pairs

    // stage 1: load x rows; own-channel h kept in regs
    float hv8[8], xin8[8];
#pragma unroll
    for (int j = 0; j < 8; ++j) {
        hv8[j] = state[(size_t)(gb + j) * UU + lane];
        buf[j][lane] = hv8[j];
    }
#pragma unroll
    for (int j = 0; j < 8; ++j) xin8[j] = inputs[gb + j];
    unsigned mgbits = 0;
#pragma unroll
    for (int j = 0; j < 8; ++j)
        mgbits |= (__shfl(hv8[j], 58, 64) != 0.0f) ? (1u << j) : 0u;
    __syncthreads();

    // stage 2: q (pre-scaled 1/8) and x@Ws + bs, 8 nodes share weight loads
    float aq[8], as_[8];
#pragma unroll
    for (int j = 0; j < 8; ++j) { aq[j] = 0.f; as_[j] = 0.f; }
    for (int f4 = 0; f4 < 16; ++f4) {
        float4 xv[8];
#pragma unroll
        for (int j = 0; j < 8; ++j) xv[j] = *(const float4*)&buf[j][f4 * 4];
#pragma unroll
        for (int ff = 0; ff < 4; ++ff) {
            int f = f4 * 4 + ff;
            float wq = Wq[f * UU + lane], ws = Ws[f * UU + lane];
#pragma unroll
            for (int j = 0; j < 8; ++j) {
                float xf = ff == 0 ? xv[j].x : ff == 1 ? xv[j].y
                         : ff == 2 ? xv[j].z : xv[j].w;
                aq[j] += xf * wq; as_[j] += xf * ws;
            }
        }
    }
    {
        float wq64 = Wq[UU * UU + lane], ws64 = Ws[UU * UU + lane];
        float bql = bq[lane], bsl = bs[lane];
#pragma unroll
        for (int j = 0; j < 8; ++j) {
            aq[j] = (aq[j] + xin8[j] * wq64 + bql) * SCALE_F;
            as_[j] += xin8[j] * ws64 + bsl;
        }
    }
    __syncthreads();                          // x reads done
#pragma unroll
    for (int j = 0; j < 8; ++j) buf[j][lane] = aq[j];   // q into slot j
    __syncthreads();

    // stage 3: per-node edge loop (wave-uniform control)
    const u16* kb = kbuf + (size_t)b * NN * UU;
    const char* vbB = (const char*)(vbuf + (size_t)b * NN * UU);
    const unsigned char* mb = maskb + (size_t)b * NN;
    const float4* pv4 = (const float4*)pv;
    float h2own[8];
    int la2 = lane << 1;

#pragma unroll 1
    for (int j = 0; j < 8; ++j) {
        float h2;
        if (mgbits & (1u << j)) {
            int n = gb + j - b * NN;
            int i0 = off[n], i1 = off[n + 1];
            i0 = max(0, min(i0, EE)); i1 = max(i0, min(i1, EE));
            float m = NEG_F, l = 0.f;
            float ac0 = 0.f, ac1 = 0.f, ac2 = 0.f, ac3 = 0.f;
            for (int i = i0; i < i1; i += 64) {
                int tlen = min(64, i1 - i);
                // phase A: lane = edge; bf16 k row (128 B) dot q
                float sc = NEG_F; bool act = false; int srow = 0;
                if (lane < tlen) {
                    int s = psrc[i + lane];
                    if ((unsigned)s < (unsigned)NN && mb[s]) {
                        srow = s; act = true;
                        const uint4* kp = (const uint4*)(kb + (size_t)s * UU);
                        float d0 = 0.f, d1 = 0.f, d2 = 0.f, d3 = 0.f;
#pragma unroll
                        for (int c = 0; c < 8; ++c) {
                            uint4 kk = kp[c];
                            float4 qa = *(const float4*)&buf[j][c * 8];
                            float4 qc = *(const float4*)&buf[j][c * 8 + 4];
                            d0 += u2f(kk.x << 16) * qa.x; d1 += u2f(kk.x & 0xFFFF0000u) * qa.y;
                            d2 += u2f(kk.y << 16) * qa.z; d3 += u2f(kk.y & 0xFFFF0000u) * qa.w;
                            d0 += u2f(kk.z << 16) * qc.x; d1 += u2f(kk.z & 0xFFFF0000u) * qc.y;
                            d2 += u2f(kk.w << 16) * qc.z; d3 += u2f(kk.w & 0xFFFF0000u) * qc.w;
                        }
                        sc = (d0 + d1) + (d2 + d3);
                    }
                }
                // tile softmax merge
                float mt = sc;
#pragma unroll
                for (int d = 1; d < 64; d <<= 1) mt = fmaxf(mt, __shfl_xor(mt, d, 64));
                float mnew = fmaxf(m, mt);
                float scale = __expf(m - mnew);
                float p = act ? __expf(sc - mnew) : 0.f;
                float ps = p;
#pragma unroll
                for (int d = 1; d < 64; d <<= 1) ps += __shfl_xor(ps, d, 64);
                l = l * scale + ps;
                m = mnew;
                // stage (p, v-row byte offset) pairs in LDS
                pv[2 * lane]     = p;
                pv[2 * lane + 1] = __int_as_float(srow * (UU * 2));
                __syncthreads();              // single-wave: cheap fence
                // phase B: lane = channel; 2 edges per ds_read_b128
                ac0 *= scale; ac1 *= scale; ac2 *= scale; ac3 *= scale;
                for (int j0 = 0; j0 < 64; j0 += 8) {
                    if (j0 >= tlen) break;    // uniform
#pragma unroll
                    for (int q4 = 0; q4 < 4; ++q4) {
                        float4 pp = pv4[(j0 >> 1) + q4];
                        float va = u2f((unsigned)*(const u16*)(vbB + (__float_as_int(pp.y) + la2)) << 16);
                        float vc = u2f((unsigned)*(const u16*)(vbB + (__float_as_int(pp.w) + la2)) << 16);
                        if (q4 == 0)      { ac0 += pp.x * va; ac0 += pp.z * vc; }
                        else if (q4 == 1) { ac1 += pp.x * va; ac1 += pp.z * vc; }
                        else if (q4 == 2) { ac2 += pp.x * va; ac2 += pp.z * vc; }
                        else              { ac3 += pp.x * va; ac3 += pp.z * vc; }
                    }
                }
                __syncthreads();              // pv reads done before next tile
            }
            float acc = (ac0 + ac1) + (ac2 + ac3);
            float agg = (l > 0.f) ? acc / fmaxf(l, 1e-16f) : 0.f;
            h2 = agg + as_[j];
        } else {
            h2 = hv8[j];                      // masked node: pass-through h
        }
        h2own[j] = h2;
    }
    __syncthreads();                          // q reads done
#pragma unroll
    for (int j = 0; j < 8; ++j) buf[j][lane] = h2own[j];
    __syncthreads();

    // stage 4: GRU. value = sigmoid([xin,h2]@W1+b1)
    float a1[8], a2[8];
#pragma unroll
    for (int j = 0; j < 8; ++j) {
        a1[j] = xin8[j] * W1[lane];
        a2[j] = xin8[j] * W1[UU + lane];
    }
    for (int f4 = 0; f4 < 16; ++f4) {
        float4 xv[8];
#pragma unroll
        for (int j = 0; j < 8; ++j) xv[j] = *(const float4*)&buf[j][f4 * 4];
#pragma unroll
        for (int ff = 0; ff < 4; ++ff) {
            int f = f4 * 4 + ff;
            float w1a = W1[(f + 1) * 128 + lane], w1b = W1[(f + 1) * 128 + UU + lane];
#pragma unroll
            for (int j = 0; j < 8; ++j) {
                float xf = ff == 0 ? xv[j].x : ff == 1 ? xv[j].y
                         : ff == 2 ? xv[j].z : xv[j].w;
                a1[j] += xf * w1a; a2[j] += xf * w1b;
            }
        }
    }
    float b1a = b1[lane], b1b = b1[UU + lane];
    float z8[8];
#pragma unroll
    for (int j = 0; j < 8; ++j) {
        float rst = 1.f / (1.f + __expf(-(a1[j] + b1a)));
        z8[j]     = 1.f / (1.f + __expf(-(a2[j] + b1b)));
        a1[j] = rst * h2own[j];               // reset*h2 (own channel)
    }
    __syncthreads();                          // h2 reads done
#pragma unroll
    for (int j = 0; j < 8; ++j) buf[j][lane] = a1[j];
    __syncthreads();

    // c = tanh([xin, reset*h2]@W2 + b2)
    float a3[8];
#pragma unroll
    for (int j = 0; j < 8; ++j) a3[j] = xin8[j] * W2[lane];
    for (int f4 = 0; f4 < 16; ++f4) {
        float4 xv[8];
#pragma unroll
        for (int j = 0; j < 8; ++j) xv[j] = *(const float4*)&buf[j][f4 * 4];
#pragma unroll
        for (int ff = 0; ff < 4; ++ff) {
            int f = f4 * 4 + ff;
            float w2v = W2[(f + 1) * UU + lane];
#pragma unroll
            for (int j = 0; j < 8; ++j) {
                float xf = ff == 0 ? xv[j].x : ff == 1 ? xv[j].y
                         : ff == 2 ? xv[j].z : xv[j].w;
                a3[j] += xf * w2v;
            }
        }
    }
    float b2l = b2[lane];
#pragma unroll
    for (int j = 0; j < 8; ++j) {
        float a = a3[j] + b2l;
        float aa = fabsf(a), tt = __expf(-2.f * aa);
        float c = copysignf((1.f - tt) / (1.f + tt), a);   // overflow-safe tanh
        out[(size_t)(gb + j) * UU + lane] = (1.f - z8[j]) * h2own[j] + z8[j] * c;
    }
}

// ------------------------------------------------------------------- launch
extern "C" void kernel_launch(void* const* d_in, const int* in_sizes, int n_in,
                              void* d_out, int out_size, void* d_ws, size_t ws_size,
                              hipStream_t stream) {
    const float* inputs = (const float*)d_in[0];
    const float* state  = (const float*)d_in[1];
    if (in_sizes[0] != BB * NN) { inputs = (const float*)d_in[1]; state = (const float*)d_in[0]; }
    const int*   esrc   = (const int*)d_in[2];
    const int*   edst   = (const int*)d_in[3];
    const float* Wq = (const float*)d_in[4];
    const float* bq = (const float*)d_in[5];
    const float* Wk = (const float*)d_in[6];
    const float* bk = (const float*)d_in[7];
    const float* Wv = (const float*)d_in[8];
    const float* bv = (const float*)d_in[9];
    const float* Ws = (const float*)d_in[10];
    const float* bs = (const float*)d_in[11];
    const float* W1 = (const float*)d_in[12];
    const float* b1 = (const float*)d_in[13];
    const float* W2 = (const float*)d_in[14];
    const float* b2 = (const float*)d_in[15];
    float* out = (float*)d_out;

    // workspace carve (~23.3 MB; r8 proved ws_size sufficient)
    char* base = (char*)d_ws;
    size_t ofs = 0;
    int* counts = (int*)(base + ofs); ofs = align_up(ofs + (size_t)NN * 4);
    int* offp   = (int*)(base + ofs); ofs = align_up(ofs + (size_t)(NN + 1) * 4);
    int* cursor = (int*)(base + ofs); ofs = align_up(ofs + (size_t)NN * 4);
    int* psrc   = (int*)(base + ofs); ofs = align_up(ofs + (size_t)EE * 4);
    unsigned char* maskb = (unsigned char*)(base + ofs); ofs = align_up(ofs + (size_t)BB * NN);
    u16* kbuf = (u16*)(base + ofs); ofs = align_up(ofs + (size_t)BB * NN * UU * 2);
    u16* vbuf = (u16*)(base + ofs); ofs = align_up(ofs + (size_t)BB * NN * UU * 2);
    (void)n_in; (void)out_size; (void)ws_size;

    hipMemsetAsync(counts, 0, (size_t)NN * 4, stream);
    hist_kernel<<<(EE + 255) / 256, 256, 0, stream>>>(edst, counts);
    scan_kernel<<<1, 1024, 0, stream>>>(counts, offp, cursor);
    scatter_kernel<<<(EE + 255) / 256, 256, 0, stream>>>(edst, esrc, cursor, psrc);
    prep_kernel<<<(BB * NN) / 8, 64, 0, stream>>>(state, inputs, Wk, bk,
                                                  Wv, bv, kbuf, vbuf, maskb);
    fused_fast<<<(BB * NN) / 8, 64, 0, stream>>>(state, inputs, Wq, bq, Ws, bs,
                                                 W1, b1, W2, b2, kbuf, vbuf,
                                                 maskb, offp, psrc, out);
}

// Round 10
// 426.076 us; speedup vs baseline: 2.1067x; 2.1067x over previous
//
#include <hip/hip_runtime.h>
#include <hip/hip_bf16.h>

// Problem constants (GraphGRUCell_62019327754706)
// DTYPES (settled r4/r5): all float tensors FP32 in and out. int32 edges.
// r6: never clamp launch_bounds waves -> spills.
// r8: 4 nodes/wave @ block=256 => VGPR 64, no spill, fused 213us.  <-- keep
// r9: 8 nodes/wave => VGPR 256, 430MB spill writes, 3x slower.     <-- never
// r10: r8 fused + register-chunked one-pass scan (was ~400 barriers).
#define BB 4
#define NN 20000
#define UU 64
#define EE 640000
#define FF 65              // U + D
#define SCALE_F 0.125f     // 1/sqrt(64)
#define NEG_F  -1e30f

typedef unsigned short u16;

static inline size_t align_up(size_t x) { return (x + 255) & ~(size_t)255; }

__device__ __forceinline__ float u2f(unsigned int u) { return __uint_as_float(u); }
__device__ __forceinline__ u16 f2bf(float f) {
    __hip_bfloat16 h = __float2bfloat16(f);
    return *reinterpret_cast<u16*>(&h);
}

// ---------------------------------------------------------------- CSR build
__global__ __launch_bounds__(256) void hist_kernel(const int* __restrict__ edst,
                                                   int* __restrict__ counts) {
    int e = blockIdx.x * 256 + threadIdx.x;
    if (e < EE) {
        int d = edst[e];
        if ((unsigned)d < (unsigned)NN) atomicAdd(&counts[d], 1);
    }
}

// One block, 20 elements/thread in registers -> single 1024-wide scan.
__global__ __launch_bounds__(1024) void scan_kernel(const int* __restrict__ counts,
                                                    int* __restrict__ off,
                                                    int* __restrict__ cursor) {
    __shared__ int sd[1024];
    int tid = threadIdx.x;
    int base = tid * 20;
    int loc[20];
    int s = 0;
#pragma unroll
    for (int k = 0; k < 20; ++k) {
        int i = base + k;
        int v = (i < NN) ? counts[i] : 0;
        loc[k] = s;                       // exclusive within thread
        s += v;
    }
    sd[tid] = s;
    __syncthreads();
    for (int d = 1; d < 1024; d <<= 1) {  // Hillis-Steele inclusive
        int t = (tid >= d) ? sd[tid - d] : 0;
        __syncthreads();
        sd[tid] += t;
        __syncthreads();
    }
    int excl = sd[tid] - s;
#pragma unroll
    for (int k = 0; k < 20; ++k) {
        int i = base + k;
        if (i < NN) { int o = excl + loc[k]; off[i] = o; cursor[i] = o; }
    }
    if (tid == 1023) off[NN] = sd[1023];  // == EE
}

__global__ __launch_bounds__(256) void scatter_kernel(const int* __restrict__ edst,
                                                      const int* __restrict__ esrc,
                                                      int* __restrict__ cursor,
                                                      int* __restrict__ psrc) {
    int e = blockIdx.x * 256 + threadIdx.x;
    if (e < EE) {
        int d = edst[e];
        if ((unsigned)d < (unsigned)NN) {
            int p = atomicAdd(&cursor[d], 1);
            if ((unsigned)p < (unsigned)EE) psrc[p] = esrc[e];
        }
    }
}

// ----------------------------- prep: k,v (bf16) + mask, 8 nodes per wave
__global__ __launch_bounds__(256) void prep_kernel(
    const float* __restrict__ state, const float* __restrict__ inputs,
    const float* __restrict__ Wk, const float* __restrict__ bk,
    const float* __restrict__ Wv, const float* __restrict__ bv,
    u16* __restrict__ kbuf, u16* __restrict__ vbuf,
    unsigned char* __restrict__ maskb) {
    int w = threadIdx.x >> 6, lane = threadIdx.x & 63;
    int gb = (blockIdx.x * 4 + w) * 8;        // 8 nodes per wave
    __shared__ float xs[4][8][66];
#pragma unroll
    for (int j = 0; j < 8; ++j) {
        int g = gb + j;
        xs[w][j][lane] = state[(size_t)g * UU + lane];
        if (lane == 0) xs[w][j][64] = inputs[g];
    }
    __syncthreads();                          // uniform

    float ak[8], av[8];
#pragma unroll
    for (int j = 0; j < 8; ++j) { ak[j] = 0.f; av[j] = 0.f; }
    for (int f = 0; f < FF; ++f) {            // weight loaded once, 8 nodes reuse
        float wk = Wk[f * UU + lane], wv = Wv[f * UU + lane];
#pragma unroll
        for (int j = 0; j < 8; ++j) {
            float xv = xs[w][j][f];
            ak[j] += xv * wk; av[j] += xv * wv;
        }
    }
    float bkl = bk[lane], bvl = bv[lane];
#pragma unroll
    for (int j = 0; j < 8; ++j) {
        int g = gb + j;
        kbuf[(size_t)g * UU + lane] = f2bf(ak[j] + bkl);
        vbuf[(size_t)g * UU + lane] = f2bf(av[j] + bvl);
        if (lane == 0) maskb[g] = (xs[w][j][58] != 0.0f) ? 1 : 0;
    }
}

// -------------------- fast fused: 4 nodes/wave, bf16 k/v gathers, GRU
__global__ __launch_bounds__(256) void fused_fast(
    const float* __restrict__ state, const float* __restrict__ inputs,
    const float* __restrict__ Wq, const float* __restrict__ bq,
    const float* __restrict__ Ws, const float* __restrict__ bs,
    const float* __restrict__ W1, const float* __restrict__ b1,
    const float* __restrict__ W2, const float* __restrict__ b2,
    const u16* __restrict__ kbuf, const u16* __restrict__ vbuf,
    const unsigned char* __restrict__ maskb,
    const int* __restrict__ off, const int* __restrict__ psrc,
    float* __restrict__ out) {
    int w = threadIdx.x >> 6, lane = threadIdx.x & 63;
    int gb = (blockIdx.x * 4 + w) * 4;        // 4 nodes per wave, same batch b
    int b = gb / NN;
    __shared__ float xs[4][4][66];            // x rows; later h2 rows
    __shared__ float qs[4][4][64];            // q rows; later reset*h2 rows

    float xin[4]; bool mg[4];
#pragma unroll
    for (int j = 0; j < 4; ++j) {
        int g = gb + j;
        xs[w][j][lane] = state[(size_t)g * UU + lane];
        if (lane == 0) xs[w][j][64] = inputs[g];
    }
    __syncthreads();                          // A (uniform)
#pragma unroll
    for (int j = 0; j < 4; ++j) { xin[j] = xs[w][j][64]; mg[j] = (xs[w][j][58] != 0.0f); }

    // q (pre-scaled) + sproj for 4 nodes; weight value loaded once
    float aq[4], as_[4];
#pragma unroll
    for (int j = 0; j < 4; ++j) { aq[j] = 0.f; as_[j] = 0.f; }
    for (int f = 0; f < FF; ++f) {
        float wq = Wq[f * UU + lane], ws = Ws[f * UU + lane];
#pragma unroll
        for (int j = 0; j < 4; ++j) {
            float xv = xs[w][j][f];
            aq[j] += xv * wq; as_[j] += xv * ws;
        }
    }
    float bql = bq[lane], bsl = bs[lane];
#pragma unroll
    for (int j = 0; j < 4; ++j) {
        aq[j] = (aq[j] + bql) * SCALE_F;
        as_[j] += bsl;
        qs[w][j][lane] = aq[j];
    }
    __syncthreads();                          // B (uniform)

    const unsigned char* mb = maskb + (size_t)b * NN;
    const u16* kb = kbuf + (size_t)b * NN * UU;
    const u16* vb = vbuf + (size_t)b * NN * UU;

#pragma unroll 1
    for (int j = 0; j < 4; ++j) {
        float h2;
        if (mg[j]) {
            int n = gb + j - b * NN;
            int i0 = off[n], i1 = off[n + 1];
            i0 = max(0, min(i0, EE)); i1 = max(i0, min(i1, EE));
            float m = NEG_F, l = 0.f;
            float ac0 = 0.f, ac1 = 0.f, ac2 = 0.f, ac3 = 0.f;
            for (int i = i0; i < i1; i += 64) {
                int tlen = min(64, i1 - i);
                // phase A: lane = edge; k row = 128 B (2 cache lines)
                float sc = NEG_F; bool act = false; int srow = 0;
                if (lane < tlen) {
                    int s = psrc[i + lane];
                    if ((unsigned)s < (unsigned)NN && mb[s]) {
                        srow = s; act = true;
                        const uint4* kp = (const uint4*)(kb + (size_t)s * UU);
                        float d0 = 0.f, d1 = 0.f, d2 = 0.f, d3 = 0.f;
#pragma unroll
                        for (int c = 0; c < 8; ++c) {
                            uint4 kk = kp[c];
                            const float4 qa = *(const float4*)&qs[w][j][c * 8];
                            const float4 qb = *(const float4*)&qs[w][j][c * 8 + 4];
                            d0 += u2f(kk.x << 16) * qa.x; d1 += u2f(kk.x & 0xFFFF0000u) * qa.y;
                            d2 += u2f(kk.y << 16) * qa.z; d3 += u2f(kk.y & 0xFFFF0000u) * qa.w;
                            d0 += u2f(kk.z << 16) * qb.x; d1 += u2f(kk.z & 0xFFFF0000u) * qb.y;
                            d2 += u2f(kk.w << 16) * qb.z; d3 += u2f(kk.w & 0xFFFF0000u) * qb.w;
                        }
                        sc = (d0 + d1) + (d2 + d3);
                    }
                }
                // tile softmax merge: 2 butterflies (max, sum)
                float mt = sc;
#pragma unroll
                for (int d = 1; d < 64; d <<= 1) mt = fmaxf(mt, __shfl_xor(mt, d, 64));
                float mnew = fmaxf(m, mt);
                float scale = __expf(m - mnew);   // m=NEG,mnew=NEG -> 1, l=0 ok
                float p = act ? __expf(sc - mnew) : 0.f;
                float ps = p;
#pragma unroll
                for (int d = 1; d < 64; d <<= 1) ps += __shfl_xor(ps, d, 64);
                l = l * scale + ps;
                m = mnew;
                // phase B: lane = channel; v rows coalesced 128 B
                ac0 *= scale; ac1 *= scale; ac2 *= scale; ac3 *= scale;
                for (int j0 = 0; j0 < 64; j0 += 8) {
                    if (j0 >= tlen) break;        // uniform
#pragma unroll
                    for (int jj = 0; jj < 8; ++jj) {
                        float pj = __shfl(p, j0 + jj, 64);
                        int   sj = __shfl(srow, j0 + jj, 64);
                        float vv = u2f((unsigned)vb[(size_t)sj * UU + lane] << 16);
                        if ((jj & 3) == 0) ac0 += pj * vv;
                        else if ((jj & 3) == 1) ac1 += pj * vv;
                        else if ((jj & 3) == 2) ac2 += pj * vv;
                        else ac3 += pj * vv;
                    }
                }
            }
            float acc = (ac0 + ac1) + (ac2 + ac3);
            float agg = (l > 0.f) ? acc / fmaxf(l, 1e-16f) : 0.f;
            h2 = agg + as_[j];
        } else {
            h2 = xs[w][j][lane];              // masked node: pass-through h
        }
        xs[w][j][lane] = h2;                  // own slot; [64]=xin preserved
    }
    __syncthreads();                          // C (uniform)

    // GRU: value = sigmoid([xin,h2]@W1+b1), c = tanh([xin,r*h2]@W2+b2)
    float a1[4], a2[4];
#pragma unroll
    for (int j = 0; j < 4; ++j) { a1[j] = xin[j] * W1[lane]; a2[j] = xin[j] * W1[UU + lane]; }
    for (int f = 0; f < UU; ++f) {
        float w1a = W1[(f + 1) * 128 + lane], w1b = W1[(f + 1) * 128 + UU + lane];
#pragma unroll
        for (int j = 0; j < 4; ++j) {
            float hv = xs[w][j][f];
            a1[j] += hv * w1a; a2[j] += hv * w1b;
        }
    }
    float b1a = b1[lane], b1b = b1[UU + lane];
    float rst[4], z[4];
#pragma unroll
    for (int j = 0; j < 4; ++j) {
        rst[j] = 1.f / (1.f + __expf(-(a1[j] + b1a)));
        z[j]   = 1.f / (1.f + __expf(-(a2[j] + b1b)));
        qs[w][j][lane] = rst[j] * xs[w][j][lane];   // reset*h2
    }
    __syncthreads();                          // D (uniform)

    float a3[4];
#pragma unroll
    for (int j = 0; j < 4; ++j) a3[j] = xin[j] * W2[lane];
    for (int f = 0; f < UU; ++f) {
        float w2v = W2[(f + 1) * UU + lane];
#pragma unroll
        for (int j = 0; j < 4; ++j) a3[j] += qs[w][j][f] * w2v;
    }
    float b2l = b2[lane];
#pragma unroll
    for (int j = 0; j < 4; ++j) {
        float a = a3[j] + b2l;
        float aa = fabsf(a), tt = __expf(-2.f * aa);
        float c = copysignf((1.f - tt) / (1.f + tt), a);
        float h2v = xs[w][j][lane];
        out[(size_t)(gb + j) * UU + lane] = (1.f - z[j]) * h2v + z[j] * c;
    }
}

// ------------------------------------------------------------------- launch
extern "C" void kernel_launch(void* const* d_in, const int* in_sizes, int n_in,
                              void* d_out, int out_size, void* d_ws, size_t ws_size,
                              hipStream_t stream) {
    const float* inputs = (const float*)d_in[0];
    const float* state  = (const float*)d_in[1];
    if (in_sizes[0] != BB * NN) { inputs = (const float*)d_in[1]; state = (const float*)d_in[0]; }
    const int*   esrc   = (const int*)d_in[2];
    const int*   edst   = (const int*)d_in[3];
    const float* Wq = (const float*)d_in[4];
    const float* bq = (const float*)d_in[5];
    const float* Wk = (const float*)d_in[6];
    const float* bk = (const float*)d_in[7];
    const float* Wv = (const float*)d_in[8];
    const float* bv = (const float*)d_in[9];
    const float* Ws = (const float*)d_in[10];
    const float* bs = (const float*)d_in[11];
    const float* W1 = (const float*)d_in[12];
    const float* b1 = (const float*)d_in[13];
    const float* W2 = (const float*)d_in[14];
    const float* b2 = (const float*)d_in[15];
    float* out = (float*)d_out;

    // workspace carve (~23.3 MB; r8 proved ws_size sufficient)
    char* base = (char*)d_ws;
    size_t ofs = 0;
    int* counts = (int*)(base + ofs); ofs = align_up(ofs + (size_t)NN * 4);
    int* offp   = (int*)(base + ofs); ofs = align_up(ofs + (size_t)(NN + 1) * 4);
    int* cursor = (int*)(base + ofs); ofs = align_up(ofs + (size_t)NN * 4);
    int* psrc   = (int*)(base + ofs); ofs = align_up(ofs + (size_t)EE * 4);
    unsigned char* maskb = (unsigned char*)(base + ofs); ofs = align_up(ofs + (size_t)BB * NN);
    u16* kbuf = (u16*)(base + ofs); ofs = align_up(ofs + (size_t)BB * NN * UU * 2);
    u16* vbuf = (u16*)(base + ofs); ofs = align_up(ofs + (size_t)BB * NN * UU * 2);
    (void)n_in; (void)out_size; (void)ws_size;

    hipMemsetAsync(counts, 0, (size_t)NN * 4, stream);
    hist_kernel<<<(EE + 255) / 256, 256, 0, stream>>>(edst, counts);
    scan_kernel<<<1, 1024, 0, stream>>>(counts, offp, cursor);
    scatter_kernel<<<(EE + 255) / 256, 256, 0, stream>>>(edst, esrc, cursor, psrc);
    prep_kernel<<<(BB * NN) / 32, 256, 0, stream>>>(state, inputs, Wk, bk,
                                                    Wv, bv, kbuf, vbuf, maskb);
    fused_fast<<<(BB * NN) / 16, 256, 0, stream>>>(state, inputs, Wq, bq,
                                                   Ws, bs, W1, b1, W2, b2,
                                                   kbuf, vbuf, maskb,
                                                   offp, psrc, out);
}